// Round 5
// baseline (51.945 us; speedup 1.0000x reference)
//
#include <hip/hip_runtime.h>

typedef __bf16 bf16x8 __attribute__((ext_vector_type(8)));
typedef float f32x4 __attribute__((ext_vector_type(4)));
typedef unsigned short u16;
typedef unsigned int u32;
typedef u32 u32x4 __attribute__((ext_vector_type(4)));
typedef u16 u16x8 __attribute__((ext_vector_type(8)));

#define AS1 __attribute__((address_space(1)))
#define AS3 __attribute__((address_space(3)))
#define GLL16(gp, lp) __builtin_amdgcn_global_load_lds((const AS1 void*)(gp), (AS3 void*)(lp), 16, 0, 0)
#define GLL4(gp, lp)  __builtin_amdgcn_global_load_lds((const AS1 void*)(gp), (AS3 void*)(lp), 4, 0, 0)

__device__ __forceinline__ u16 f32_to_bf16_rne(float f) {
    union { float f; unsigned u; } cv; cv.f = f;
    unsigned u = cv.u;
    return (u16)((u + 0x7FFFu + ((u >> 16) & 1u)) >> 16);
}

__device__ __forceinline__ u32 cvt_pk_bf16(float lo, float hi) {
    u32 r;
    asm("v_cvt_pk_bf16_f32 %0, %1, %2" : "=v"(r) : "v"(lo), "v"(hi));
    return r;
}

// ---- repack w into bf16, fragment-contiguous order (unchanged, proven) ----
__global__ void repack_w_kernel(const float* __restrict__ w, u16* __restrict__ w3) {
    int e = blockIdx.x * 256 + threadIdx.x;   // 65536 total
    int j    = e & 7;
    int g    = (e >> 3) & 3;
    int o    = (e >> 5) & 127;
    int cb   = (e >> 12) & 1;
    int koff = (e >> 13) & 7;
    int c = (cb << 5) + (g << 3) + j;
    w3[e] = f32_to_bf16_rne(w[(o << 9) + (c << 3) + koff]);
}

// ---- prepass: x (NCDHW fp32) -> xT bf16 chunk layout ----
// Per (b,d,h) slab (bid = b*1089 + d*33 + h):
//   xT[bid*2048 + cc*256 + w*8 + j] = bf16(x[b][cc*8+j][d][h][w]), w=0..31
//   x32[bid*64 + cc*8 + j]          = bf16(x[b][cc*8+j][d][h][32])
// Slab = 4096 B contiguous == byte-identical to the conv kernel's LDS tile.
__global__ __launch_bounds__(256) void transpose_x_kernel(
    const float* __restrict__ x, u16* __restrict__ xT, u16* __restrict__ x32) {

    __shared__ float t[64][34];
    const int bid = blockIdx.x;            // 4356 = 4*33*33
    const int h = bid % 33;
    const int dq = bid / 33;
    const int d = dq % 33;
    const int b = dq / 33;
    const float* xp = x + (size_t)b * 2299968 + d * 1089 + h * 33;

    const int tid = threadIdx.x;
    const int wv  = tid & 31;
    const int c0  = tid >> 5;
#pragma unroll
    for (int i = 0; i < 8; ++i) {
        int c = c0 + (i << 3);
        t[c][wv] = xp[(size_t)c * 35937 + wv];
    }
    if (tid < 64) t[tid][32] = xp[(size_t)tid * 35937 + 32];
    __syncthreads();

    const int cc = tid >> 5;               // 0..7
    u32x4 v;
    v[0] = cvt_pk_bf16(t[cc * 8 + 0][wv], t[cc * 8 + 1][wv]);
    v[1] = cvt_pk_bf16(t[cc * 8 + 2][wv], t[cc * 8 + 3][wv]);
    v[2] = cvt_pk_bf16(t[cc * 8 + 4][wv], t[cc * 8 + 5][wv]);
    v[3] = cvt_pk_bf16(t[cc * 8 + 6][wv], t[cc * 8 + 7][wv]);
    *reinterpret_cast<u32x4*>(&xT[(size_t)bid * 2048 + cc * 256 + wv * 8]) = v;

    if (tid < 8) {
        u32x4 m;
        m[0] = cvt_pk_bf16(t[tid * 8 + 0][32], t[tid * 8 + 1][32]);
        m[1] = cvt_pk_bf16(t[tid * 8 + 2][32], t[tid * 8 + 3][32]);
        m[2] = cvt_pk_bf16(t[tid * 8 + 4][32], t[tid * 8 + 5][32]);
        m[3] = cvt_pk_bf16(t[tid * 8 + 6][32], t[tid * 8 + 7][32]);
        *reinterpret_cast<u32x4*>(&x32[(size_t)bid * 64 + tid * 8]) = m;
    }
}

// ---- conv kernel, global_load_lds staging ----
// LDS: 6 main slabs of 4096 B (u16 idx slab*2048 + cc*256 + w*8 + j)
//      + mini (w=32) 768 B at byte 24576 (u16 idx 12288 + kd*192 + kh*64 + cc*8)
__global__ __launch_bounds__(256, 4) void conv_mfma_kernel(
    const u16* __restrict__ xT, const u16* __restrict__ x32,
    const u16* __restrict__ w3, float* __restrict__ out) {

    __shared__ __align__(16) u16 xs[12672];   // 25344 B

    const int tid = threadIdx.x;
    const int bid = blockIdx.x;
    const int hy0 = (bid & 15) << 1;    // 2 output h-rows per block
    const int dz  = (bid >> 4) & 31;
    const int b   = bid >> 9;

    // ---- stage: 6 slab copies, each thread one 16B lane-linear issue/slab ----
    char* ldsb = (char*)xs;
    const int wave_off = (tid >> 6) << 10;     // wave-uniform within wave
#pragma unroll
    for (int s = 0; s < 6; ++s) {
        const int kd = (s >= 3) ? 1 : 0;
        const int kh = s - kd * 3;
        const size_t gslab = (size_t)(b * 1089 + (dz + kd) * 33 + (hy0 + kh));
        const char* src = (const char*)xT + (gslab << 12) + (tid << 4);
        GLL16(src, ldsb + (s << 12) + wave_off + ((tid & 63) << 4));
    }
    // mini: 768 B = two 384B chunks (kd 0/1), 192 threads x 4B, lane-linear
    if (tid < 192) {
        const int kd = tid / 96;
        const int r  = (tid << 2) - kd * 384;   // byte within chunk
        const char* src = (const char*)x32
            + ((size_t)(b * 1089 + (dz + kd) * 33 + hy0) << 7) + r;
        GLL4(src, ldsb + 24576 + ((tid >> 6) << 8) + ((tid & 63) << 2));
    }
    asm volatile("s_waitcnt vmcnt(0)" ::: "memory");
    __syncthreads();

    const int lane = tid & 63;
    const int ln   = lane & 15;
    const int g    = lane >> 4;
    const int n0w  = (tid >> 6) << 5;   // wave id * 32 = wave's o-base

    f32x4 acc[2][4];
#pragma unroll
    for (int nf = 0; nf < 2; ++nf)
#pragma unroll
        for (int mf = 0; mf < 4; ++mf)
            acc[nf][mf] = (f32x4){0.f, 0.f, 0.f, 0.f};

    // K-loop: k = koff*64 + cb*32 + g*8 + j
#pragma unroll
    for (int cb = 0; cb < 2; ++cb) {
        const int cc = (cb << 2) + g;          // c chunk 0..7
#pragma unroll
        for (int kd = 0; kd < 2; ++kd) {
            bf16x8 wf[2][4];
#pragma unroll
            for (int nf = 0; nf < 2; ++nf)
#pragma unroll
                for (int kk = 0; kk < 4; ++kk) {
                    const int koff = (kd << 2) + kk;
                    const u16* p = w3 + (size_t)((((koff << 1) + cb) << 7)
                                   + n0w + (nf << 4) + ln) * 32 + (g << 3);
                    wf[nf][kk] = __builtin_bit_cast(bf16x8, *reinterpret_cast<const u16x8*>(p));
                }
#pragma unroll
            for (int kw = 0; kw < 2; ++kw) {
                bf16x8 xf[3][2];
#pragma unroll
                for (int hh = 0; hh < 3; ++hh)
#pragma unroll
                    for (int wh = 0; wh < 2; ++wh) {
                        const int row = (wh << 4) + ln + kw;
                        const u16* p = (row < 32)
                            ? &xs[(((kd * 3 + hh) << 11)) + (cc << 8) + (row << 3)]
                            : &xs[12288 + kd * 192 + hh * 64 + (cc << 3)];
                        xf[hh][wh] = __builtin_bit_cast(bf16x8,
                            *reinterpret_cast<const u16x8*>(p));
                    }
#pragma unroll
                for (int kh = 0; kh < 2; ++kh)
#pragma unroll
                    for (int nf = 0; nf < 2; ++nf)
#pragma unroll
                        for (int mf = 0; mf < 4; ++mf)
                            acc[nf][mf] = __builtin_amdgcn_mfma_f32_16x16x32_bf16(
                                wf[nf][(kh << 1) + kw], xf[(mf >> 1) + kh][mf & 1],
                                acc[nf][mf], 0, 0, 0);
            }
        }
    }

    // ---- epilogue: out[b][n][dz][hy0+hrow][wx] = (y+1)^2 ----
    float* ob = out + ((size_t)b * 128) * 32768 + (dz << 10) + (hy0 << 5);
#pragma unroll
    for (int nf = 0; nf < 2; ++nf)
#pragma unroll
        for (int mf = 0; mf < 4; ++mf) {
            const int wx   = ((mf & 1) << 4) + ln;
            const int hrow = mf >> 1;
            float* o2 = ob + (hrow << 5) + wx;
#pragma unroll
            for (int r = 0; r < 4; ++r) {
                const int n = n0w + (nf << 4) + (g << 2) + r;
                float v = acc[nf][mf][r] + 1.0f;
                o2[(size_t)n << 15] = v * v;
            }
        }
}

// ================= fallback path (round-4, proven) for small ws =================
#define XS_ROW 72
__global__ __launch_bounds__(256, 4) void conv_mfma_fallback(
    const float* __restrict__ x, const u16* __restrict__ w3, float* __restrict__ out) {

    __shared__ __align__(16) u16 xs[6 * 33 * XS_ROW];

    const int tid = threadIdx.x;
    const int bid = blockIdx.x;
    const int hy0 = (bid & 15) << 1;
    const int dz  = (bid >> 4) & 31;
    const int b   = bid >> 9;

    const float* xb = x + (size_t)b * 64 * 35937;
    for (int i = tid; i < 1584; i += 256) {
        int w   = i % 33;
        int t   = i / 33;
        int q   = t & 7;
        int kh3 = t >> 3;
        int kd  = kh3 >= 3 ? 1 : 0;
        int kh  = kh3 - kd * 3;
        const float* p = xb + (size_t)(q << 3) * 35937 + (dz + kd) * 1089 + (hy0 + kh) * 33 + w;
        u32x4 v;
        v[0] = cvt_pk_bf16(p[0], p[35937]);
        v[1] = cvt_pk_bf16(p[2 * 35937], p[3 * 35937]);
        v[2] = cvt_pk_bf16(p[4 * 35937], p[5 * 35937]);
        v[3] = cvt_pk_bf16(p[6 * 35937], p[7 * 35937]);
        *reinterpret_cast<u32x4*>(&xs[(kh3 * 33 + w) * XS_ROW + (q << 3)]) = v;
    }
    __syncthreads();

    const int lane = tid & 63;
    const int ln   = lane & 15;
    const int g    = lane >> 4;
    const int n0w  = (tid >> 6) << 5;

    f32x4 acc[2][4];
#pragma unroll
    for (int nf = 0; nf < 2; ++nf)
#pragma unroll
        for (int mf = 0; mf < 4; ++mf)
            acc[nf][mf] = (f32x4){0.f, 0.f, 0.f, 0.f};

#pragma unroll
    for (int cb = 0; cb < 2; ++cb) {
        const int cbase = (cb << 5) + (g << 3);
#pragma unroll
        for (int kd = 0; kd < 2; ++kd) {
            bf16x8 wf[2][4];
#pragma unroll
            for (int nf = 0; nf < 2; ++nf)
#pragma unroll
                for (int kk = 0; kk < 4; ++kk) {
                    const int koff = (kd << 2) + kk;
                    const u16* p = w3 + (size_t)((((koff << 1) + cb) << 7)
                                   + n0w + (nf << 4) + ln) * 32 + (g << 3);
                    wf[nf][kk] = __builtin_bit_cast(bf16x8, *reinterpret_cast<const u16x8*>(p));
                }
#pragma unroll
            for (int kw = 0; kw < 2; ++kw) {
                bf16x8 xf[3][2];
#pragma unroll
                for (int hh = 0; hh < 3; ++hh)
#pragma unroll
                    for (int wh = 0; wh < 2; ++wh) {
                        const int row = (kd * 3 + hh) * 33 + (wh << 4) + ln + kw;
                        xf[hh][wh] = __builtin_bit_cast(bf16x8,
                            *reinterpret_cast<const u16x8*>(&xs[row * XS_ROW + cbase]));
                    }
#pragma unroll
                for (int kh = 0; kh < 2; ++kh)
#pragma unroll
                    for (int nf = 0; nf < 2; ++nf)
#pragma unroll
                        for (int mf = 0; mf < 4; ++mf)
                            acc[nf][mf] = __builtin_amdgcn_mfma_f32_16x16x32_bf16(
                                wf[nf][(kh << 1) + kw], xf[(mf >> 1) + kh][mf & 1],
                                acc[nf][mf], 0, 0, 0);
            }
        }
    }

    float* ob = out + ((size_t)b * 128) * 32768 + (dz << 10) + (hy0 << 5);
#pragma unroll
    for (int nf = 0; nf < 2; ++nf)
#pragma unroll
        for (int mf = 0; mf < 4; ++mf) {
            const int wx   = ((mf & 1) << 4) + ln;
            const int hrow = mf >> 1;
            float* o2 = ob + (hrow << 5) + wx;
#pragma unroll
            for (int r = 0; r < 4; ++r) {
                const int n = n0w + (nf << 4) + (g << 2) + r;
                float v = acc[nf][mf][r] + 1.0f;
                o2[(size_t)n << 15] = v * v;
            }
        }
}

extern "C" void kernel_launch(void* const* d_in, const int* in_sizes, int n_in,
                              void* d_out, int out_size, void* d_ws, size_t ws_size,
                              hipStream_t stream) {
    const float* x = (const float*)d_in[0];
    const float* w = (const float*)d_in[1];
    float* out = (float*)d_out;

    // ws layout: [w3: 128KB][xT: 4356*4096 B][x32: 4356*128 B]
    const size_t W3_BYTES  = 131072;
    const size_t XT_BYTES  = (size_t)4356 * 4096;
    const size_t X32_BYTES = (size_t)4356 * 128;
    const size_t NEED = W3_BYTES + XT_BYTES + X32_BYTES;

    u16* w3 = (u16*)d_ws;
    repack_w_kernel<<<256, 256, 0, stream>>>(w, w3);

    if (ws_size >= NEED) {
        u16* xT  = (u16*)((char*)d_ws + W3_BYTES);
        u16* x32 = (u16*)((char*)d_ws + W3_BYTES + XT_BYTES);
        transpose_x_kernel<<<4356, 256, 0, stream>>>(x, xT, x32);
        conv_mfma_kernel<<<2048, 256, 0, stream>>>(xT, x32, w3, out);
    } else {
        conv_mfma_fallback<<<2048, 256, 0, stream>>>(x, w3, out);
    }
}

// Round 6
// 47.309 us; speedup vs baseline: 1.0980x; 1.0980x over previous
//
#include <hip/hip_runtime.h>

typedef __bf16 bf16x8 __attribute__((ext_vector_type(8)));
typedef float f32x4 __attribute__((ext_vector_type(4)));
typedef unsigned short u16;
typedef unsigned int u32;
typedef u32 u32x4 __attribute__((ext_vector_type(4)));
typedef u16 u16x8 __attribute__((ext_vector_type(8)));

#define AS1 __attribute__((address_space(1)))
#define AS3 __attribute__((address_space(3)))
#define GLL16(gp, lp) __builtin_amdgcn_global_load_lds((const AS1 void*)(gp), (AS3 void*)(lp), 16, 0, 0)

__device__ __forceinline__ u16 f32_to_bf16_rne(float f) {
    union { float f; unsigned u; } cv; cv.f = f;
    unsigned u = cv.u;
    return (u16)((u + 0x7FFFu + ((u >> 16) & 1u)) >> 16);
}

__device__ __forceinline__ u32 cvt_pk_bf16(float lo, float hi) {
    u32 r;
    asm("v_cvt_pk_bf16_f32 %0, %1, %2" : "=v"(r) : "v"(lo), "v"(hi));
    return r;
}

// ---- repack w into bf16, fragment-contiguous order (proven) ----
// w3[(((koff*2+cb)*128 + o)*4 + g)*8 + j] = bf16(w[o*512 + c*8 + koff])
__global__ void repack_w_kernel(const float* __restrict__ w, u16* __restrict__ w3) {
    int e = blockIdx.x * 256 + threadIdx.x;   // 65536 total
    int j    = e & 7;
    int g    = (e >> 3) & 3;
    int o    = (e >> 5) & 127;
    int cb   = (e >> 12) & 1;
    int koff = (e >> 13) & 7;
    int c = (cb << 5) + (g << 3) + j;
    w3[e] = f32_to_bf16_rne(w[(o << 9) + (c << 3) + koff]);
}

// ---- prepass: direct register transpose (no LDS round-trip) ----
// xT[bid*2048 + cc*256 + w*8 + j] = bf16(x[b][cc*8+j][d][h][w]), w=0..31
// x32[bid*64 + cc*8 + j]          = bf16(x[b][cc*8+j][d][h][32])
__global__ __launch_bounds__(256) void transpose_x_kernel(
    const float* __restrict__ x, u16* __restrict__ xT, u16* __restrict__ x32) {

    const int bid = blockIdx.x;            // 4356 = 4*33*33
    const int h = bid % 33;
    const int dq = bid / 33;
    const int d = dq % 33;
    const int b = dq / 33;
    const float* xp = x + (size_t)b * 2299968 + d * 1089 + h * 33;

    const int tid = threadIdx.x;
    const int wv  = tid & 31;
    const int cc  = tid >> 5;              // 0..7
    const float* p = xp + (size_t)cc * 8 * 35937 + wv;   // lanes wv: coalesced 128B per j
    float f0 = p[0],              f1 = p[35937],          f2 = p[2 * 35937], f3 = p[3 * 35937];
    float f4 = p[(size_t)4*35937],f5 = p[(size_t)5*35937],f6 = p[(size_t)6*35937],f7 = p[(size_t)7*35937];
    u32x4 v;
    v[0] = cvt_pk_bf16(f0, f1);
    v[1] = cvt_pk_bf16(f2, f3);
    v[2] = cvt_pk_bf16(f4, f5);
    v[3] = cvt_pk_bf16(f6, f7);
    *reinterpret_cast<u32x4*>(&xT[(size_t)bid * 2048 + cc * 256 + wv * 8]) = v;

    if (tid < 8) {                         // w = 32 column
        const float* q = xp + (size_t)tid * 8 * 35937 + 32;
        u32x4 m;
        m[0] = cvt_pk_bf16(q[0],              q[35937]);
        m[1] = cvt_pk_bf16(q[2 * 35937],      q[3 * 35937]);
        m[2] = cvt_pk_bf16(q[(size_t)4*35937],q[(size_t)5*35937]);
        m[3] = cvt_pk_bf16(q[(size_t)6*35937],q[(size_t)7*35937]);
        *reinterpret_cast<u32x4*>(&x32[(size_t)bid * 64 + tid * 8]) = m;
    }
}

// ---- conv: dz-paired, 8-wave o-split, global_load_lds staging ----
// LDS: 9 main slabs (d=dz0..dz0+2 x h=hy0..hy0+2) of 4096B, slab_id = s*3+hh,
//      u16 idx slab_id*2048 + cc*256 + row*8;
//      mini (w=32) at u16 18432 + s*192 + hh*64 + cc*8.  Total 38016 B.
__global__ __launch_bounds__(512, 4) void conv_mfma_kernel(
    const u16* __restrict__ xT, const u16* __restrict__ x32,
    const u16* __restrict__ w3, float* __restrict__ out) {

    __shared__ __align__(16) u16 xs[19008];

    const int tid = threadIdx.x;
    const int bid = blockIdx.x;            // 1024 = 4b * 16dzp * 16hy
    const int hy0 = (bid & 15) << 1;
    const int dz0 = ((bid >> 4) & 15) << 1;
    const int b   = bid >> 8;

    // ---- stage 9 main slabs: 2304 x 16B units, 512 threads, 4.5 rounds.
    // dest = ldsb + u*16 (lane-linear); src slab = base + s*33 + hh.
    char* ldsb = (char*)xs;
    const int slab0 = b * 1089 + dz0 * 33 + hy0;
#pragma unroll
    for (int r = 0; r < 5; ++r) {
        if (r == 4 && tid >= 256) continue;          // waves 4..7 uniformly skip
        const int u   = tid + (r << 9);
        const int sid = u >> 8;                      // 0..8, wave-uniform
        const int s   = (sid * 171) >> 9;            // sid/3
        const int hh  = sid - s * 3;
        const char* src = (const char*)xT + ((size_t)(slab0 + s * 33 + hh) << 12)
                          + ((u & 255) << 4);
        GLL16(src, ldsb + (u << 4));
    }
    // mini: 9 x 128B = 72 x 16B; per d a contiguous 384B chunk (3 h-slabs).
    if (tid < 72) {
        const int s  = (tid * 171) >> 12;            // tid/24
        const int rr = tid - s * 24;
        const char* src = (const char*)x32
            + ((size_t)(b * 1089 + (dz0 + s) * 33 + hy0) << 7) + (rr << 4);
        GLL16(src, ldsb + 36864 + (tid << 4));
    }
    asm volatile("s_waitcnt vmcnt(0)" ::: "memory");
    __syncthreads();

    const int lane = tid & 63;
    const int ln   = lane & 15;
    const int g    = lane >> 4;
    const int o0   = (tid >> 6) << 4;      // wave's o-base (16 o's per wave)

    f32x4 acc0[4], acc1[4];                // outputs dz0 / dz0+1
#pragma unroll
    for (int mf = 0; mf < 4; ++mf) {
        acc0[mf] = (f32x4){0.f, 0.f, 0.f, 0.f};
        acc1[mf] = (f32x4){0.f, 0.f, 0.f, 0.f};
    }

    // K-loop with wf rotation: slab s serves out0 as kd'=s (s<2) and
    // out1 as kd'=s-1 (s>=1). wfA = kd'=0 frags, wfB = kd'=1 frags.
#pragma unroll
    for (int cb = 0; cb < 2; ++cb) {
        const int cc = (cb << 2) + g;
        bf16x8 wfA[4], wfB[4];
#pragma unroll
        for (int kk = 0; kk < 4; ++kk) {   // kd'=0: koff = kk
            const u16* p = w3 + ((size_t)(((kk << 1) + cb) * 128 + o0 + ln) << 5) + (g << 3);
            wfA[kk] = __builtin_bit_cast(bf16x8, *reinterpret_cast<const u16x8*>(p));
        }
#pragma unroll
        for (int s = 0; s < 3; ++s) {
            if (s == 1) {
#pragma unroll
                for (int kk = 0; kk < 4; ++kk) {   // kd'=1: koff = 4+kk
                    const u16* p = w3 + ((size_t)((((4 + kk) << 1) + cb) * 128 + o0 + ln) << 5) + (g << 3);
                    wfB[kk] = __builtin_bit_cast(bf16x8, *reinterpret_cast<const u16x8*>(p));
                }
            }
#pragma unroll
            for (int kw = 0; kw < 2; ++kw) {
                bf16x8 xf[3][2];
#pragma unroll
                for (int hh = 0; hh < 3; ++hh)
#pragma unroll
                    for (int wh = 0; wh < 2; ++wh) {
                        const int row = (wh << 4) + ln + kw;
                        const u16* p = (row < 32)
                            ? &xs[((s * 3 + hh) << 11) + (cc << 8) + (row << 3)]
                            : &xs[18432 + s * 192 + hh * 64 + (cc << 3)];
                        xf[hh][wh] = __builtin_bit_cast(bf16x8,
                            *reinterpret_cast<const u16x8*>(p));
                    }
#pragma unroll
                for (int kh = 0; kh < 2; ++kh) {
                    const int kk = (kh << 1) + kw;
#pragma unroll
                    for (int mf = 0; mf < 4; ++mf) {
                        const bf16x8 xv = xf[(mf >> 1) + kh][mf & 1];
                        if (s < 2)
                            acc0[mf] = __builtin_amdgcn_mfma_f32_16x16x32_bf16(
                                (s == 0 ? wfA : wfB)[kk], xv, acc0[mf], 0, 0, 0);
                        if (s >= 1)
                            acc1[mf] = __builtin_amdgcn_mfma_f32_16x16x32_bf16(
                                (s == 1 ? wfA : wfB)[kk], xv, acc1[mf], 0, 0, 0);
                    }
                }
            }
        }
    }

    // ---- epilogue: out[b][n][dz0+od][hy0+hrow][wx] = (y+1)^2 ----
    float* ob = out + (size_t)b * 128 * 32768 + ((size_t)dz0 << 10) + (hy0 << 5);
#pragma unroll
    for (int mf = 0; mf < 4; ++mf) {
        const int wx   = ((mf & 1) << 4) + ln;
        const int hrow = mf >> 1;
#pragma unroll
        for (int r = 0; r < 4; ++r) {
            const int n = o0 + (g << 2) + r;
            float* o2 = ob + ((size_t)n << 15) + (hrow << 5) + wx;
            float v0 = acc0[mf][r] + 1.0f;
            o2[0] = v0 * v0;
            float v1 = acc1[mf][r] + 1.0f;
            o2[1024] = v1 * v1;
        }
    }
}

// ================= fallback path (round-4, proven) for small ws =================
#define XS_ROW 72
__global__ __launch_bounds__(256, 4) void conv_mfma_fallback(
    const float* __restrict__ x, const u16* __restrict__ w3, float* __restrict__ out) {

    __shared__ __align__(16) u16 xs[6 * 33 * XS_ROW];

    const int tid = threadIdx.x;
    const int bid = blockIdx.x;
    const int hy0 = (bid & 15) << 1;
    const int dz  = (bid >> 4) & 31;
    const int b   = bid >> 9;

    const float* xb = x + (size_t)b * 64 * 35937;
    for (int i = tid; i < 1584; i += 256) {
        int w   = i % 33;
        int t   = i / 33;
        int q   = t & 7;
        int kh3 = t >> 3;
        int kd  = kh3 >= 3 ? 1 : 0;
        int kh  = kh3 - kd * 3;
        const float* p = xb + (size_t)(q << 3) * 35937 + (dz + kd) * 1089 + (hy0 + kh) * 33 + w;
        u32x4 v;
        v[0] = cvt_pk_bf16(p[0], p[35937]);
        v[1] = cvt_pk_bf16(p[2 * 35937], p[3 * 35937]);
        v[2] = cvt_pk_bf16(p[4 * 35937], p[5 * 35937]);
        v[3] = cvt_pk_bf16(p[6 * 35937], p[7 * 35937]);
        *reinterpret_cast<u32x4*>(&xs[(kh3 * 33 + w) * XS_ROW + (q << 3)]) = v;
    }
    __syncthreads();

    const int lane = tid & 63;
    const int ln   = lane & 15;
    const int g    = lane >> 4;
    const int n0w  = (tid >> 6) << 5;

    f32x4 acc[2][4];
#pragma unroll
    for (int nf = 0; nf < 2; ++nf)
#pragma unroll
        for (int mf = 0; mf < 4; ++mf)
            acc[nf][mf] = (f32x4){0.f, 0.f, 0.f, 0.f};

#pragma unroll
    for (int cb = 0; cb < 2; ++cb) {
        const int cbase = (cb << 5) + (g << 3);
#pragma unroll
        for (int kd = 0; kd < 2; ++kd) {
            bf16x8 wf[2][4];
#pragma unroll
            for (int nf = 0; nf < 2; ++nf)
#pragma unroll
                for (int kk = 0; kk < 4; ++kk) {
                    const int koff = (kd << 2) + kk;
                    const u16* p = w3 + (size_t)((((koff << 1) + cb) << 7)
                                   + n0w + (nf << 4) + ln) * 32 + (g << 3);
                    wf[nf][kk] = __builtin_bit_cast(bf16x8, *reinterpret_cast<const u16x8*>(p));
                }
#pragma unroll
            for (int kw = 0; kw < 2; ++kw) {
                bf16x8 xf[3][2];
#pragma unroll
                for (int hh = 0; hh < 3; ++hh)
#pragma unroll
                    for (int wh = 0; wh < 2; ++wh) {
                        const int row = (kd * 3 + hh) * 33 + (wh << 4) + ln + kw;
                        xf[hh][wh] = __builtin_bit_cast(bf16x8,
                            *reinterpret_cast<const u16x8*>(&xs[row * XS_ROW + cbase]));
                    }
#pragma unroll
                for (int kh = 0; kh < 2; ++kh)
#pragma unroll
                    for (int nf = 0; nf < 2; ++nf)
#pragma unroll
                        for (int mf = 0; mf < 4; ++mf)
                            acc[nf][mf] = __builtin_amdgcn_mfma_f32_16x16x32_bf16(
                                wf[nf][(kh << 1) + kw], xf[(mf >> 1) + kh][mf & 1],
                                acc[nf][mf], 0, 0, 0);
            }
        }
    }

    float* ob = out + ((size_t)b * 128) * 32768 + (dz << 10) + (hy0 << 5);
#pragma unroll
    for (int nf = 0; nf < 2; ++nf)
#pragma unroll
        for (int mf = 0; mf < 4; ++mf) {
            const int wx   = ((mf & 1) << 4) + ln;
            const int hrow = mf >> 1;
            float* o2 = ob + (hrow << 5) + wx;
#pragma unroll
            for (int r = 0; r < 4; ++r) {
                const int n = n0w + (nf << 4) + (g << 2) + r;
                float v = acc[nf][mf][r] + 1.0f;
                o2[(size_t)n << 15] = v * v;
            }
        }
}

extern "C" void kernel_launch(void* const* d_in, const int* in_sizes, int n_in,
                              void* d_out, int out_size, void* d_ws, size_t ws_size,
                              hipStream_t stream) {
    const float* x = (const float*)d_in[0];
    const float* w = (const float*)d_in[1];
    float* out = (float*)d_out;

    // ws layout: [w3: 128KB][xT: 4356*4096 B][x32: 4356*128 B]
    const size_t W3_BYTES  = 131072;
    const size_t XT_BYTES  = (size_t)4356 * 4096;
    const size_t X32_BYTES = (size_t)4356 * 128;
    const size_t NEED = W3_BYTES + XT_BYTES + X32_BYTES;

    u16* w3 = (u16*)d_ws;
    repack_w_kernel<<<256, 256, 0, stream>>>(w, w3);

    if (ws_size >= NEED) {
        u16* xT  = (u16*)((char*)d_ws + W3_BYTES);
        u16* x32 = (u16*)((char*)d_ws + W3_BYTES + XT_BYTES);
        transpose_x_kernel<<<4356, 256, 0, stream>>>(x, xT, x32);
        conv_mfma_kernel<<<1024, 512, 0, stream>>>(xT, x32, w3, out);
    } else {
        conv_mfma_fallback<<<2048, 256, 0, stream>>>(x, w3, out);
    }
}

// Round 7
// 45.875 us; speedup vs baseline: 1.1323x; 1.0313x over previous
//
#include <hip/hip_runtime.h>

typedef __bf16 bf16x8 __attribute__((ext_vector_type(8)));
typedef float f32x4 __attribute__((ext_vector_type(4)));
typedef unsigned short u16;
typedef unsigned int u32;
typedef u32 u32x4 __attribute__((ext_vector_type(4)));
typedef u16 u16x8 __attribute__((ext_vector_type(8)));

#define AS1 __attribute__((address_space(1)))
#define AS3 __attribute__((address_space(3)))
#define GLL16(gp, lp) __builtin_amdgcn_global_load_lds((const AS1 void*)(gp), (AS3 void*)(lp), 16, 0, 0)

__device__ __forceinline__ u16 f32_to_bf16_rne(float f) {
    union { float f; unsigned u; } cv; cv.f = f;
    unsigned u = cv.u;
    return (u16)((u + 0x7FFFu + ((u >> 16) & 1u)) >> 16);
}

__device__ __forceinline__ u32 cvt_pk_bf16(float lo, float hi) {
    u32 r;
    asm("v_cvt_pk_bf16_f32 %0, %1, %2" : "=v"(r) : "v"(lo), "v"(hi));
    return r;
}

// ---- repack w into bf16, fragment-contiguous order (proven) ----
// w3[(((koff*2+cb)*128 + o)*4 + g)*8 + j] = bf16(w[o*512 + c*8 + koff])
__global__ void repack_w_kernel(const float* __restrict__ w, u16* __restrict__ w3) {
    int e = blockIdx.x * 256 + threadIdx.x;   // 65536 total
    int j    = e & 7;
    int g    = (e >> 3) & 3;
    int o    = (e >> 5) & 127;
    int cb   = (e >> 12) & 1;
    int koff = (e >> 13) & 7;
    int c = (cb << 5) + (g << 3) + j;
    w3[e] = f32_to_bf16_rne(w[(o << 9) + (c << 3) + koff]);
}

// ---- prepass: direct register transpose (proven) ----
// xT[bid*2048 + cc*256 + w*8 + j] = bf16(x[b][cc*8+j][d][h][w]), w=0..31
// x32[bid*64 + cc*8 + j]          = bf16(x[b][cc*8+j][d][h][32])
__global__ __launch_bounds__(256) void transpose_x_kernel(
    const float* __restrict__ x, u16* __restrict__ xT, u16* __restrict__ x32) {

    const int bid = blockIdx.x;            // 4356 = 4*33*33
    const int h = bid % 33;
    const int dq = bid / 33;
    const int d = dq % 33;
    const int b = dq / 33;
    const float* xp = x + (size_t)b * 2299968 + d * 1089 + h * 33;

    const int tid = threadIdx.x;
    const int wv  = tid & 31;
    const int cc  = tid >> 5;              // 0..7
    const float* p = xp + (size_t)cc * 8 * 35937 + wv;
    float f0 = p[0],              f1 = p[35937],          f2 = p[2 * 35937], f3 = p[3 * 35937];
    float f4 = p[(size_t)4*35937],f5 = p[(size_t)5*35937],f6 = p[(size_t)6*35937],f7 = p[(size_t)7*35937];
    u32x4 v;
    v[0] = cvt_pk_bf16(f0, f1);
    v[1] = cvt_pk_bf16(f2, f3);
    v[2] = cvt_pk_bf16(f4, f5);
    v[3] = cvt_pk_bf16(f6, f7);
    *reinterpret_cast<u32x4*>(&xT[(size_t)bid * 2048 + cc * 256 + wv * 8]) = v;

    if (tid < 8) {                         // w = 32 column
        const float* q = xp + (size_t)tid * 8 * 35937 + 32;
        u32x4 m;
        m[0] = cvt_pk_bf16(q[0],              q[35937]);
        m[1] = cvt_pk_bf16(q[2 * 35937],      q[3 * 35937]);
        m[2] = cvt_pk_bf16(q[(size_t)4*35937],q[(size_t)5*35937]);
        m[3] = cvt_pk_bf16(q[(size_t)6*35937],q[(size_t)7*35937]);
        *reinterpret_cast<u32x4*>(&x32[(size_t)bid * 64 + tid * 8]) = m;
    }
}

// ---- conv: dz-QUAD, 8-wave o-split, global_load_lds staging ----
// LDS: 15 main slabs (d=dz0..dz0+4 x h=hy0..hy0+2) of 4096B, slab_id = s*3+hh,
//      u16 idx slab_id*2048 + cc*256 + row*8;
//      mini (w=32) at u16 30720 + s*192 + hh*64 + cc*8.  Total 63360 B.
__global__ __launch_bounds__(512, 4) void conv_mfma_kernel(
    const u16* __restrict__ xT, const u16* __restrict__ x32,
    const u16* __restrict__ w3, float* __restrict__ out) {

    __shared__ __align__(16) u16 xs[31680];

    const int tid = threadIdx.x;
    const int bid = blockIdx.x;            // 512 = 4b * 8dzq * 16hy
    const int hy0 = (bid & 15) << 1;
    const int dz0 = ((bid >> 4) & 7) << 2;
    const int b   = bid >> 7;

    // ---- stage 15 main slabs: 3840 x 16B units, 512 threads, 7.5 rounds ----
    char* ldsb = (char*)xs;
    const int slab0 = b * 1089 + dz0 * 33 + hy0;
#pragma unroll
    for (int r = 0; r < 8; ++r) {
        if (r == 7 && tid >= 256) continue;          // waves 4..7 uniformly skip
        const int u   = tid + (r << 9);
        const int sid = u >> 8;                      // 0..14, wave-uniform
        const int s   = (sid * 171) >> 9;            // sid/3
        const int hh  = sid - s * 3;
        const char* src = (const char*)xT + ((size_t)(slab0 + s * 33 + hh) << 12)
                          + ((u & 255) << 4);
        GLL16(src, ldsb + (u << 4));
    }
    // mini: 15 x 128B = 120 x 16B; per d a contiguous 384B chunk (3 h-slabs).
    if (tid < 120) {
        const int s  = (tid * 171) >> 12;            // tid/24
        const int rr = tid - s * 24;
        const char* src = (const char*)x32
            + ((size_t)(b * 1089 + (dz0 + s) * 33 + hy0) << 7) + (rr << 4);
        GLL16(src, ldsb + 61440 + (tid << 4));
    }
    asm volatile("s_waitcnt vmcnt(0)" ::: "memory");
    __syncthreads();

    const int lane = tid & 63;
    const int ln   = lane & 15;
    const int g    = lane >> 4;
    const int o0   = (tid >> 6) << 4;      // wave's o-base (16 o's per wave)

    f32x4 acc[4][4];                       // [out dz][mf]
#pragma unroll
    for (int od = 0; od < 4; ++od)
#pragma unroll
        for (int mf = 0; mf < 4; ++mf)
            acc[od][mf] = (f32x4){0.f, 0.f, 0.f, 0.f};

    // K-loop, wf rotation: slab s serves out s (kd'=0, wfA) and out s-1
    // (kd'=1, wfB). xf live-set kept to 2 frags: hh outermost, each xf
    // consumed immediately by its (kh, hrow=hh-kh) pairs.
#pragma unroll
    for (int cb = 0; cb < 2; ++cb) {
        const int cc = (cb << 2) + g;
        bf16x8 wfA[4], wfB[4];
#pragma unroll
        for (int kk = 0; kk < 4; ++kk) {   // kd'=0: koff = kk
            const u16* p = w3 + ((size_t)(((kk << 1) + cb) * 128 + o0 + ln) << 5) + (g << 3);
            wfA[kk] = __builtin_bit_cast(bf16x8, *reinterpret_cast<const u16x8*>(p));
        }
#pragma unroll
        for (int s = 0; s < 5; ++s) {
            if (s == 1) {
#pragma unroll
                for (int kk = 0; kk < 4; ++kk) {   // kd'=1: koff = 4+kk
                    const u16* p = w3 + ((size_t)((((4 + kk) << 1) + cb) * 128 + o0 + ln) << 5) + (g << 3);
                    wfB[kk] = __builtin_bit_cast(bf16x8, *reinterpret_cast<const u16x8*>(p));
                }
            }
#pragma unroll
            for (int kw = 0; kw < 2; ++kw) {
#pragma unroll
                for (int hh = 0; hh < 3; ++hh) {
                    bf16x8 xf[2];
#pragma unroll
                    for (int wh = 0; wh < 2; ++wh) {
                        const int row = (wh << 4) + ln + kw;
                        const u16* p = (row < 32)
                            ? &xs[((s * 3 + hh) << 11) + (cc << 8) + (row << 3)]
                            : &xs[30720 + s * 192 + hh * 64 + (cc << 3)];
                        xf[wh] = __builtin_bit_cast(bf16x8,
                            *reinterpret_cast<const u16x8*>(p));
                    }
#pragma unroll
                    for (int kh = 0; kh < 2; ++kh) {
                        const int hrow = hh - kh;
                        if (hrow < 0 || hrow > 1) continue;
                        const int kk = (kh << 1) + kw;
#pragma unroll
                        for (int wh = 0; wh < 2; ++wh) {
                            const int mf = (hrow << 1) + wh;
                            if (s < 4)
                                acc[s][mf] = __builtin_amdgcn_mfma_f32_16x16x32_bf16(
                                    wfA[kk], xf[wh], acc[s][mf], 0, 0, 0);
                            if (s >= 1)
                                acc[s - 1][mf] = __builtin_amdgcn_mfma_f32_16x16x32_bf16(
                                    wfB[kk], xf[wh], acc[s - 1][mf], 0, 0, 0);
                        }
                    }
                }
            }
        }
    }

    // ---- epilogue: out[b][n][dz0+od][hy0+hrow][wx] = (y+1)^2 ----
    float* ob = out + (size_t)b * 128 * 32768 + ((size_t)dz0 << 10) + (hy0 << 5);
#pragma unroll
    for (int mf = 0; mf < 4; ++mf) {
        const int wx   = ((mf & 1) << 4) + ln;
        const int hrow = mf >> 1;
#pragma unroll
        for (int r = 0; r < 4; ++r) {
            const int n = o0 + (g << 2) + r;
            float* o2 = ob + ((size_t)n << 15) + (hrow << 5) + wx;
#pragma unroll
            for (int od = 0; od < 4; ++od) {
                float v = acc[od][mf][r] + 1.0f;
                o2[od << 10] = v * v;
            }
        }
    }
}

// ================= fallback path (round-4, proven) for small ws =================
#define XS_ROW 72
__global__ __launch_bounds__(256, 4) void conv_mfma_fallback(
    const float* __restrict__ x, const u16* __restrict__ w3, float* __restrict__ out) {

    __shared__ __align__(16) u16 xs[6 * 33 * XS_ROW];

    const int tid = threadIdx.x;
    const int bid = blockIdx.x;
    const int hy0 = (bid & 15) << 1;
    const int dz  = (bid >> 4) & 31;
    const int b   = bid >> 9;

    const float* xb = x + (size_t)b * 64 * 35937;
    for (int i = tid; i < 1584; i += 256) {
        int w   = i % 33;
        int t   = i / 33;
        int q   = t & 7;
        int kh3 = t >> 3;
        int kd  = kh3 >= 3 ? 1 : 0;
        int kh  = kh3 - kd * 3;
        const float* p = xb + (size_t)(q << 3) * 35937 + (dz + kd) * 1089 + (hy0 + kh) * 33 + w;
        u32x4 v;
        v[0] = cvt_pk_bf16(p[0], p[35937]);
        v[1] = cvt_pk_bf16(p[2 * 35937], p[3 * 35937]);
        v[2] = cvt_pk_bf16(p[4 * 35937], p[5 * 35937]);
        v[3] = cvt_pk_bf16(p[6 * 35937], p[7 * 35937]);
        *reinterpret_cast<u32x4*>(&xs[(kh3 * 33 + w) * XS_ROW + (q << 3)]) = v;
    }
    __syncthreads();

    const int lane = tid & 63;
    const int ln   = lane & 15;
    const int g    = lane >> 4;
    const int n0w  = (tid >> 6) << 5;

    f32x4 acc[2][4];
#pragma unroll
    for (int nf = 0; nf < 2; ++nf)
#pragma unroll
        for (int mf = 0; mf < 4; ++mf)
            acc[nf][mf] = (f32x4){0.f, 0.f, 0.f, 0.f};

#pragma unroll
    for (int cb = 0; cb < 2; ++cb) {
        const int cbase = (cb << 5) + (g << 3);
#pragma unroll
        for (int kd = 0; kd < 2; ++kd) {
            bf16x8 wf[2][4];
#pragma unroll
            for (int nf = 0; nf < 2; ++nf)
#pragma unroll
                for (int kk = 0; kk < 4; ++kk) {
                    const int koff = (kd << 2) + kk;
                    const u16* p = w3 + (size_t)((((koff << 1) + cb) << 7)
                                   + n0w + (nf << 4) + ln) * 32 + (g << 3);
                    wf[nf][kk] = __builtin_bit_cast(bf16x8, *reinterpret_cast<const u16x8*>(p));
                }
#pragma unroll
            for (int kw = 0; kw < 2; ++kw) {
                bf16x8 xf[3][2];
#pragma unroll
                for (int hh = 0; hh < 3; ++hh)
#pragma unroll
                    for (int wh = 0; wh < 2; ++wh) {
                        const int row = (kd * 3 + hh) * 33 + (wh << 4) + ln + kw;
                        xf[hh][wh] = __builtin_bit_cast(bf16x8,
                            *reinterpret_cast<const u16x8*>(&xs[row * XS_ROW + cbase]));
                    }
#pragma unroll
                for (int kh = 0; kh < 2; ++kh)
#pragma unroll
                    for (int nf = 0; nf < 2; ++nf)
#pragma unroll
                        for (int mf = 0; mf < 4; ++mf)
                            acc[nf][mf] = __builtin_amdgcn_mfma_f32_16x16x32_bf16(
                                wf[nf][(kh << 1) + kw], xf[(mf >> 1) + kh][mf & 1],
                                acc[nf][mf], 0, 0, 0);
            }
        }
    }

    float* ob = out + ((size_t)b * 128) * 32768 + (dz << 10) + (hy0 << 5);
#pragma unroll
    for (int nf = 0; nf < 2; ++nf)
#pragma unroll
        for (int mf = 0; mf < 4; ++mf) {
            const int wx   = ((mf & 1) << 4) + ln;
            const int hrow = mf >> 1;
            float* o2 = ob + (hrow << 5) + wx;
#pragma unroll
            for (int r = 0; r < 4; ++r) {
                const int n = n0w + (nf << 4) + (g << 2) + r;
                float v = acc[nf][mf][r] + 1.0f;
                o2[(size_t)n << 15] = v * v;
            }
        }
}

extern "C" void kernel_launch(void* const* d_in, const int* in_sizes, int n_in,
                              void* d_out, int out_size, void* d_ws, size_t ws_size,
                              hipStream_t stream) {
    const float* x = (const float*)d_in[0];
    const float* w = (const float*)d_in[1];
    float* out = (float*)d_out;

    // ws layout: [w3: 128KB][xT: 4356*4096 B][x32: 4356*128 B]
    const size_t W3_BYTES  = 131072;
    const size_t XT_BYTES  = (size_t)4356 * 4096;
    const size_t X32_BYTES = (size_t)4356 * 128;
    const size_t NEED = W3_BYTES + XT_BYTES + X32_BYTES;

    u16* w3 = (u16*)d_ws;
    repack_w_kernel<<<256, 256, 0, stream>>>(w, w3);

    if (ws_size >= NEED) {
        u16* xT  = (u16*)((char*)d_ws + W3_BYTES);
        u16* x32 = (u16*)((char*)d_ws + W3_BYTES + XT_BYTES);
        transpose_x_kernel<<<4356, 256, 0, stream>>>(x, xT, x32);
        conv_mfma_kernel<<<512, 512, 0, stream>>>(xT, x32, w3, out);
    } else {
        conv_mfma_fallback<<<2048, 256, 0, stream>>>(x, w3, out);
    }
}